// Round 3
// baseline (125.476 us; speedup 1.0000x reference)
//
#include <hip/hip_runtime.h>

#define POOL 7
#define NUM_ROIS 300
#define FH 200
#define FW 200
#define FC 512

typedef float f4 __attribute__((ext_vector_type(4)));  // native vector: OK for nontemporal builtins

// One block per (roi, py) output row: 128 threads x f4 = 512 channels,
// unrolled loop over the 7 px cells -> 28 independent loads in flight per
// wave, L1 reuse of shared bilinear corner columns, 14 KB contiguous store.
__global__ __launch_bounds__(128) void roi_pool_row_kernel(
    const float* __restrict__ feat,   // (FH, FW, FC) fp32, NHWC
    const int*   __restrict__ rois,   // (NUM_ROIS, 4) int32: x0,y0,w,h
    float*       __restrict__ out)    // (NUM_ROIS, POOL, POOL, FC) fp32
{
    const int b  = blockIdx.x;                 // 0 .. NUM_ROIS*POOL-1
    const int r  = b / POOL;
    const int py = b - r * POOL;

    const int x0 = rois[4 * r + 0];
    const int y0 = rois[4 * r + 1];
    const int w  = rois[4 * r + 2];
    const int h  = rois[4 * r + 3];

    // Match reference arithmetic exactly: sy = py*(h/7), sx = px*(w/7), fp32.
    const float hq = (float)h / 7.0f;
    const float wq = (float)w / 7.0f;

    const float sy   = (float)py * hq;
    const int   y_lo = (int)floorf(sy);
    const int   y_hi = min(y_lo + 1, h - 1);
    const float fy   = sy - (float)y_lo;

    const size_t row_lo = (size_t)(y0 + y_lo) * FW;
    const size_t row_hi = (size_t)(y0 + y_hi) * FW;

    const int t = threadIdx.x;                 // 0..127, one f4 lane slot
    f4* __restrict__ obase =
        (f4*)(out + ((size_t)r * (POOL * POOL) + (size_t)py * POOL) * FC);

#pragma unroll
    for (int px = 0; px < POOL; ++px) {
        const float sx   = (float)px * wq;
        const int   x_lo = (int)floorf(sx);
        const int   x_hi = min(x_lo + 1, w - 1);
        const float fx   = sx - (float)x_lo;

        const float w00 = (1.0f - fy) * (1.0f - fx);
        const float w01 = (1.0f - fy) * fx;
        const float w10 = fy * (1.0f - fx);
        const float w11 = fy * fx;

        const f4* __restrict__ f00 = (const f4*)(feat + (row_lo + (x0 + x_lo)) * FC);
        const f4* __restrict__ f01 = (const f4*)(feat + (row_lo + (x0 + x_hi)) * FC);
        const f4* __restrict__ f10 = (const f4*)(feat + (row_hi + (x0 + x_lo)) * FC);
        const f4* __restrict__ f11 = (const f4*)(feat + (row_hi + (x0 + x_hi)) * FC);

        const f4 v00 = f00[t];
        const f4 v01 = f01[t];
        const f4 v10 = f10[t];
        const f4 v11 = f11[t];

        const f4 res = v00 * w00 + v01 * w01 + v10 * w10 + v11 * w11;

        // Write-once stream: non-temporal so it doesn't evict feature rows in L2.
        __builtin_nontemporal_store(res, &obase[(size_t)px * (FC / 4) + t]);
    }
}

extern "C" void kernel_launch(void* const* d_in, const int* in_sizes, int n_in,
                              void* d_out, int out_size, void* d_ws, size_t ws_size,
                              hipStream_t stream) {
    const float* feat = (const float*)d_in[0];  // (1,200,200,512) fp32
    const int*   rois = (const int*)d_in[1];    // (1,300,4) int32
    float*       out  = (float*)d_out;          // (1,300,7,7,512) fp32

    const int n_rows = NUM_ROIS * POOL;         // 2100 blocks
    roi_pool_row_kernel<<<n_rows, 128, 0, stream>>>(feat, rois, out);
}